// Round 1
// baseline (615.421 us; speedup 1.0000x reference)
//
#include <hip/hip_runtime.h>

#define F      128
#define TILE   128
#define KSTEP  32
#define NCHUNKS 96
#define TOPK   3

#define DINF (__builtin_inff())
#define IMAX 0x7fffffff

__device__ __forceinline__ bool lex_less(float d1, int i1, float d2, int i2) {
    return (d1 < d2) || (d1 == d2 && i1 < i2);
}

// --- phase 0: row squared norms (one wave per row, float2 per lane) ---
__global__ void rownorm_kernel(const float* __restrict__ src, float* __restrict__ dst, int rows) {
    int row  = blockIdx.x * 4 + (threadIdx.x >> 6);
    int lane = threadIdx.x & 63;
    if (row >= rows) return;
    float2 v = *reinterpret_cast<const float2*>(&src[(size_t)row * F + lane * 2]);
    float s = v.x * v.x + v.y * v.y;
    #pragma unroll
    for (int m = 32; m >= 1; m >>= 1) s += __shfl_xor(s, m, 64);
    if (lane == 0) dst[row] = s;
}

// --- phase 1: fused fp32 GEMM tile + distance + per-thread top-3 + block reduce ---
__global__ __launch_bounds__(256, 2) void knn_phase1(
    const float* __restrict__ X, const float* __restrict__ Qm,
    const float* __restrict__ x2, const float* __restrict__ q2,
    float* __restrict__ part_d, int* __restrict__ part_i,
    int N, int ntiles)
{
    __shared__ __align__(16) union {
        struct { float a[KSTEP][TILE]; float b[KSTEP][TILE]; } s;   // 32 KB
        struct { float d[TILE][16][TOPK]; int i[TILE][16][TOPK]; } r; // 48 KB
    } u;

    const int t  = threadIdx.x;
    const int tx = t & 15;
    const int ty = t >> 4;
    const int r0 = ty * 8;      // query rows (within tile) owned by this thread
    const int c0 = tx * 8;      // data cols  (within tile) owned by this thread
    const int chunk = blockIdx.x;
    const int qbase = blockIdx.y * TILE;

    float t3d[8][TOPK];
    int   t3i[8][TOPK];
    #pragma unroll
    for (int i = 0; i < 8; i++)
        #pragma unroll
        for (int c = 0; c < TOPK; c++) { t3d[i][c] = DINF; t3i[i][c] = IMAX; }

    float q2r[8];
    #pragma unroll
    for (int i = 0; i < 8; i++) q2r[i] = q2[qbase + r0 + i];

    for (int tile = chunk; tile < ntiles; tile += NCHUNKS) {
        float acc[8][8];
        #pragma unroll
        for (int i = 0; i < 8; i++)
            #pragma unroll
            for (int j = 0; j < 8; j++) acc[i][j] = 0.0f;

        for (int ks = 0; ks < F; ks += KSTEP) {
            __syncthreads();
            // stage A (queries) and B (data) into LDS, k-major layout
            #pragma unroll
            for (int l = 0; l < 4; l++) {
                int f   = t + 256 * l;   // float4 id 0..1023
                int row = f >> 3;        // 0..127
                int kc  = f & 7;         // float4 column within KSTEP

                float4 va = *reinterpret_cast<const float4*>(
                    &Qm[(size_t)(qbase + row) * F + ks + kc * 4]);
                u.s.a[kc * 4 + 0][row] = va.x;
                u.s.a[kc * 4 + 1][row] = va.y;
                u.s.a[kc * 4 + 2][row] = va.z;
                u.s.a[kc * 4 + 3][row] = va.w;

                int n = tile * TILE + row;
                float4 vb = make_float4(0.f, 0.f, 0.f, 0.f);
                if (n < N) vb = *reinterpret_cast<const float4*>(
                    &X[(size_t)n * F + ks + kc * 4]);
                u.s.b[kc * 4 + 0][row] = vb.x;
                u.s.b[kc * 4 + 1][row] = vb.y;
                u.s.b[kc * 4 + 2][row] = vb.z;
                u.s.b[kc * 4 + 3][row] = vb.w;
            }
            __syncthreads();

            #pragma unroll
            for (int kk = 0; kk < KSTEP; kk++) {
                float4 a0 = *reinterpret_cast<const float4*>(&u.s.a[kk][r0]);
                float4 a1 = *reinterpret_cast<const float4*>(&u.s.a[kk][r0 + 4]);
                float4 b0 = *reinterpret_cast<const float4*>(&u.s.b[kk][c0]);
                float4 b1 = *reinterpret_cast<const float4*>(&u.s.b[kk][c0 + 4]);
                float av[8] = {a0.x, a0.y, a0.z, a0.w, a1.x, a1.y, a1.z, a1.w};
                float bv[8] = {b0.x, b0.y, b0.z, b0.w, b1.x, b1.y, b1.z, b1.w};
                #pragma unroll
                for (int i = 0; i < 8; i++)
                    #pragma unroll
                    for (int j = 0; j < 8; j++)
                        acc[i][j] = fmaf(av[i], bv[j], acc[i][j]);
            }
        }

        // epilogue: distances + per-thread sorted top-3 (indices scanned ascending)
        #pragma unroll
        for (int j = 0; j < 8; j++) {
            int n = tile * TILE + c0 + j;
            if (n < N) {
                float xc = x2[n];
                #pragma unroll
                for (int i = 0; i < 8; i++) {
                    // matches np: (q2 - 2*dot) + x2  (2*acc exact; fma = same rounding)
                    float d = (q2r[i] - 2.0f * acc[i][j]) + xc;
                    if (d < t3d[i][2]) {
                        t3d[i][2] = d; t3i[i][2] = n;
                        if (t3d[i][2] < t3d[i][1]) {
                            float td = t3d[i][2]; t3d[i][2] = t3d[i][1]; t3d[i][1] = td;
                            int ti = t3i[i][2]; t3i[i][2] = t3i[i][1]; t3i[i][1] = ti;
                        }
                        if (t3d[i][1] < t3d[i][0]) {
                            float td = t3d[i][1]; t3d[i][1] = t3d[i][0]; t3d[i][0] = td;
                            int ti = t3i[i][1]; t3i[i][1] = t3i[i][0]; t3i[i][0] = ti;
                        }
                    }
                }
            }
        }
    }

    // block reduce: 16 col-threads per query row -> 3 candidates per (row, chunk)
    __syncthreads();
    #pragma unroll
    for (int i = 0; i < 8; i++)
        #pragma unroll
        for (int c = 0; c < TOPK; c++) {
            u.r.d[r0 + i][tx][c] = t3d[i][c];
            u.r.i[r0 + i][tx][c] = t3i[i][c];
        }
    __syncthreads();

    if (t < TILE) {
        int row = t;
        float b0d = DINF, b1d = DINF, b2d = DINF;
        int   b0i = IMAX, b1i = IMAX, b2i = IMAX;
        for (int s = 0; s < 16; s++) {
            #pragma unroll
            for (int c = 0; c < TOPK; c++) {
                float d = u.r.d[row][s][c];
                int  ix = u.r.i[row][s][c];
                if (lex_less(d, ix, b2d, b2i)) {
                    b2d = d; b2i = ix;
                    if (lex_less(b2d, b2i, b1d, b1i)) {
                        float td = b2d; b2d = b1d; b1d = td;
                        int ti = b2i; b2i = b1i; b1i = ti;
                    }
                    if (lex_less(b1d, b1i, b0d, b0i)) {
                        float td = b1d; b1d = b0d; b0d = td;
                        int ti = b1i; b1i = b0i; b0i = ti;
                    }
                }
            }
        }
        size_t base = ((size_t)(qbase + row) * NCHUNKS + chunk) * TOPK;
        part_d[base + 0] = b0d; part_d[base + 1] = b1d; part_d[base + 2] = b2d;
        part_i[base + 0] = b0i; part_i[base + 1] = b1i; part_i[base + 2] = b2i;
    }
}

// --- phase 2: merge per-chunk candidates, gather labels, write both outputs ---
__global__ void knn_phase2(const float* __restrict__ part_d, const int* __restrict__ part_i,
                           const float* __restrict__ Y, float* __restrict__ out, int Q)
{
    int q    = blockIdx.x * 4 + (threadIdx.x >> 6);
    int lane = threadIdx.x & 63;
    if (q >= Q) return;

    float b0d = DINF, b1d = DINF, b2d = DINF;
    int   b0i = IMAX, b1i = IMAX, b2i = IMAX;

    auto ins = [&](float d, int ix) {
        if (lex_less(d, ix, b2d, b2i)) {
            b2d = d; b2i = ix;
            if (lex_less(b2d, b2i, b1d, b1i)) {
                float td = b2d; b2d = b1d; b1d = td;
                int ti = b2i; b2i = b1i; b1i = ti;
            }
            if (lex_less(b1d, b1i, b0d, b0i)) {
                float td = b1d; b1d = b0d; b0d = td;
                int ti = b1i; b1i = b0i; b0i = ti;
            }
        }
    };

    const int total = NCHUNKS * TOPK;
    size_t base = (size_t)q * total;
    for (int e = lane; e < total; e += 64)
        ins(part_d[base + e], part_i[base + e]);

    #pragma unroll
    for (int m = 1; m < 64; m <<= 1) {
        float od0 = __shfl_xor(b0d, m, 64); int oi0 = __shfl_xor(b0i, m, 64);
        float od1 = __shfl_xor(b1d, m, 64); int oi1 = __shfl_xor(b1i, m, 64);
        float od2 = __shfl_xor(b2d, m, 64); int oi2 = __shfl_xor(b2i, m, 64);
        ins(od0, oi0); ins(od1, oi1); ins(od2, oi2);
    }

    if (lane == 0) {
        int idx_off = Q * 3;
        #pragma unroll
        for (int c = 0; c < 3; c++) {
            float s = Y[(size_t)b0i * 3 + c] + Y[(size_t)b1i * 3 + c] + Y[(size_t)b2i * 3 + c];
            out[q * 3 + c] = s / 3.0f;
        }
        out[idx_off + q * 3 + 0] = (float)b0i;
        out[idx_off + q * 3 + 1] = (float)b1i;
        out[idx_off + q * 3 + 2] = (float)b2i;
    }
}

extern "C" void kernel_launch(void* const* d_in, const int* in_sizes, int n_in,
                              void* d_out, int out_size, void* d_ws, size_t ws_size,
                              hipStream_t stream) {
    const float* X  = (const float*)d_in[0];  // [N,128]
    const float* Y  = (const float*)d_in[1];  // [N,3]
    const float* Qm = (const float*)d_in[2];  // [Q,128]
    int N = in_sizes[1] / 3;
    int Q = in_sizes[2] / F;
    int ntiles = (N + TILE - 1) / TILE;

    char* ws = (char*)d_ws;
    size_t o = 0;
    auto alloc = [&](size_t bytes) { size_t r = o; o = (o + bytes + 255) & ~(size_t)255; return r; };
    float* x2     = (float*)(ws + alloc((size_t)N * 4));
    float* q2     = (float*)(ws + alloc((size_t)Q * 4));
    float* part_d = (float*)(ws + alloc((size_t)Q * NCHUNKS * TOPK * 4));
    int*   part_i = (int*)  (ws + alloc((size_t)Q * NCHUNKS * TOPK * 4));

    hipLaunchKernelGGL(rownorm_kernel, dim3((N + 3) / 4), dim3(256), 0, stream, X, x2, N);
    hipLaunchKernelGGL(rownorm_kernel, dim3((Q + 3) / 4), dim3(256), 0, stream, Qm, q2, Q);
    hipLaunchKernelGGL(knn_phase1, dim3(NCHUNKS, Q / TILE), dim3(256), 0, stream,
                       X, Qm, x2, q2, part_d, part_i, N, ntiles);
    hipLaunchKernelGGL(knn_phase2, dim3((Q + 3) / 4), dim3(256), 0, stream,
                       part_d, part_i, Y, (float*)d_out, Q);
}